// Round 2
// baseline (496.316 us; speedup 1.0000x reference)
//
#include <hip/hip_runtime.h>

// 2-qubit gate (qubits 5,12) on a 24-qubit fp32 state, batch=4 innermost.
// float4-unit index: q5 -> bit 18, q12 -> bit 11.
// One thread handles 2 consecutive float4 (32 B) x 4 amplitude slots
// = 128 B read + 128 B write, for higher MLP and fewer threads.
// Pair-unit (32 B) index: q5 -> bit 17, q12 -> bit 10.

typedef float fvec4 __attribute__((ext_vector_type(4)));

__global__ __launch_bounds__(256) void apply_2q_gate(
    const fvec4* __restrict__ in,
    const float* __restrict__ pauli,   // 4x4 row-major [out][in]
    fvec4* __restrict__ out)
{
    const unsigned h = blockIdx.x * 256u + threadIdx.x;   // [0, 2^21)

    // Insert zero bits at pair-bit 10 (q12) and pair-bit 17 (q5).
    const unsigned low  =  h         & ((1u << 10) - 1u);   // bits 0..9
    const unsigned mid  = (h >> 10)  & ((1u << 6)  - 1u);   // 6 bits
    const unsigned high =  h >> 16;                          // 5 bits
    const unsigned pair = low | (mid << 11) | (high << 18);
    const unsigned base = pair << 1;          // float4 units
    const unsigned S1 = 1u << 11;             // q12 stride (float4 units)
    const unsigned S0 = 1u << 18;             // q5 stride  (float4 units)

    // Slot order j = j0*2 + j1 (j0 = q5 bit, j1 = q12 bit) = pauli column.
    fvec4 a[4][2];
    a[0][0] = in[base];           a[0][1] = in[base + 1];
    a[1][0] = in[base + S1];      a[1][1] = in[base + S1 + 1];
    a[2][0] = in[base + S0];      a[2][1] = in[base + S0 + 1];
    a[3][0] = in[base + S0 + S1]; a[3][1] = in[base + S0 + S1 + 1];

    float p[16];
#pragma unroll
    for (int i = 0; i < 16; ++i) p[i] = pauli[i];

#pragma unroll
    for (int i = 0; i < 4; ++i) {
        const unsigned off = base + ((unsigned)i >> 1) * S0 + ((unsigned)i & 1u) * S1;
#pragma unroll
        for (int v = 0; v < 2; ++v) {
            fvec4 r;
            r.x = p[4*i+0]*a[0][v].x + p[4*i+1]*a[1][v].x + p[4*i+2]*a[2][v].x + p[4*i+3]*a[3][v].x;
            r.y = p[4*i+0]*a[0][v].y + p[4*i+1]*a[1][v].y + p[4*i+2]*a[2][v].y + p[4*i+3]*a[3][v].y;
            r.z = p[4*i+0]*a[0][v].z + p[4*i+1]*a[1][v].z + p[4*i+2]*a[2][v].z + p[4*i+3]*a[3][v].z;
            r.w = p[4*i+0]*a[0][v].w + p[4*i+1]*a[1][v].w + p[4*i+2]*a[2][v].w + p[4*i+3]*a[3][v].w;
            __builtin_nontemporal_store(r, &out[off + (unsigned)v]);
        }
    }
}

extern "C" void kernel_launch(void* const* d_in, const int* in_sizes, int n_in,
                              void* d_out, int out_size, void* d_ws, size_t ws_size,
                              hipStream_t stream) {
    const fvec4* state = (const fvec4*)d_in[0];   // 2^24 float4
    const float* pauli = (const float*)d_in[1];   // 16 floats
    fvec4* out = (fvec4*)d_out;

    const unsigned n_thr = 1u << 21;              // one per 32-B pair-group
    const unsigned block = 256;
    const unsigned grid  = n_thr / block;         // 8192 blocks

    apply_2q_gate<<<grid, block, 0, stream>>>(state, pauli, out);
}

// Round 3
// 423.273 us; speedup vs baseline: 1.1726x; 1.1726x over previous
//
#include <hip/hip_runtime.h>

// 2-qubit gate (qubits 5,12) on a 24-qubit fp32 state, batch=4 innermost.
// float4-unit index: q5 -> bit 18, q12 -> bit 11.
// One thread handles 2 consecutive float4 (32 B) x 4 amplitude slots
// = 128 B read + 128 B write. Plain stores (NT stores caused 1.6x HBM
// write amplification by defeating L2 write-combining — round 2 counters).

typedef float fvec4 __attribute__((ext_vector_type(4)));

__global__ __launch_bounds__(256) void apply_2q_gate(
    const fvec4* __restrict__ in,
    const float* __restrict__ pauli,   // 4x4 row-major [out][in]
    fvec4* __restrict__ out)
{
    const unsigned h = blockIdx.x * 256u + threadIdx.x;   // [0, 2^21)

    // Insert zero bits at pair-bit 10 (q12) and pair-bit 17 (q5).
    const unsigned low  =  h         & ((1u << 10) - 1u);   // bits 0..9
    const unsigned mid  = (h >> 10)  & ((1u << 6)  - 1u);   // 6 bits
    const unsigned high =  h >> 16;                          // 5 bits
    const unsigned pair = low | (mid << 11) | (high << 18);
    const unsigned base = pair << 1;          // float4 units
    const unsigned S1 = 1u << 11;             // q12 stride (float4 units)
    const unsigned S0 = 1u << 18;             // q5 stride  (float4 units)

    // Slot order j = j0*2 + j1 (j0 = q5 bit, j1 = q12 bit) = pauli column.
    fvec4 a[4][2];
    a[0][0] = in[base];           a[0][1] = in[base + 1];
    a[1][0] = in[base + S1];      a[1][1] = in[base + S1 + 1];
    a[2][0] = in[base + S0];      a[2][1] = in[base + S0 + 1];
    a[3][0] = in[base + S0 + S1]; a[3][1] = in[base + S0 + S1 + 1];

    float p[16];
#pragma unroll
    for (int i = 0; i < 16; ++i) p[i] = pauli[i];

#pragma unroll
    for (int i = 0; i < 4; ++i) {
        const unsigned off = base + ((unsigned)i >> 1) * S0 + ((unsigned)i & 1u) * S1;
#pragma unroll
        for (int v = 0; v < 2; ++v) {
            fvec4 r;
            r.x = p[4*i+0]*a[0][v].x + p[4*i+1]*a[1][v].x + p[4*i+2]*a[2][v].x + p[4*i+3]*a[3][v].x;
            r.y = p[4*i+0]*a[0][v].y + p[4*i+1]*a[1][v].y + p[4*i+2]*a[2][v].y + p[4*i+3]*a[3][v].y;
            r.z = p[4*i+0]*a[0][v].z + p[4*i+1]*a[1][v].z + p[4*i+2]*a[2][v].z + p[4*i+3]*a[3][v].z;
            r.w = p[4*i+0]*a[0][v].w + p[4*i+1]*a[1][v].w + p[4*i+2]*a[2][v].w + p[4*i+3]*a[3][v].w;
            out[off + (unsigned)v] = r;
        }
    }
}

extern "C" void kernel_launch(void* const* d_in, const int* in_sizes, int n_in,
                              void* d_out, int out_size, void* d_ws, size_t ws_size,
                              hipStream_t stream) {
    const fvec4* state = (const fvec4*)d_in[0];   // 2^24 float4
    const float* pauli = (const float*)d_in[1];   // 16 floats
    fvec4* out = (fvec4*)d_out;

    const unsigned n_thr = 1u << 21;              // one per 32-B pair-group
    const unsigned block = 256;
    const unsigned grid  = n_thr / block;         // 8192 blocks

    apply_2q_gate<<<grid, block, 0, stream>>>(state, pauli, out);
}